// Round 1
// baseline (344.918 us; speedup 1.0000x reference)
//
#include <hip/hip_runtime.h>

#define NN 1536
#define NE 49152
#define NM (NE + NN)      // edges + self loops = 50688
#define FIN 27
#define HD 64
#define LDIM 32
#define PP 1178880        // NN*(NN-1)/2

#define EL_OFF  (NN*FIN)            // 41472
#define MU_OFF  (EL_OFF + PP)       // 1220352
#define LV_OFF  (MU_OFF + NN*LDIM)  // 1269504
#define GMU_OFF (LV_OFF + NN*LDIM)  // 1318656
#define GLV_OFF (GMU_OFF + LDIM)    // 1318688

__device__ __forceinline__ float wsum(float v) {
#pragma unroll
  for (int m = 1; m < 64; m <<= 1) v += __shfl_xor(v, m, 64);
  return v;
}

// ---------------- CSR construction ----------------
__global__ void gvae_degree(const int* __restrict__ ei, int* __restrict__ deg) {
  int e = blockIdx.x * 256 + threadIdx.x;
  if (e < NM) {
    int dst = (e < NE) ? ei[NE + e] : (e - NE);
    atomicAdd(&deg[dst], 1);
  }
}

__global__ void gvae_scan(int* __restrict__ deg, int* __restrict__ rowptr) {
  __shared__ int sh[256];
  int t = threadIdx.x;
  int base = t * 6;
  int v[6]; int s = 0;
#pragma unroll
  for (int r = 0; r < 6; r++) { v[r] = deg[base + r]; s += v[r]; }
  sh[t] = s; __syncthreads();
  for (int off = 1; off < 256; off <<= 1) {
    int x = (t >= off) ? sh[t - off] : 0;
    __syncthreads();
    sh[t] += x;
    __syncthreads();
  }
  int run = sh[t] - s;
#pragma unroll
  for (int r = 0; r < 6; r++) { rowptr[base + r] = run; deg[base + r] = run; run += v[r]; }
  if (t == 255) rowptr[NN] = run;
}

__global__ void gvae_scatter(const int* __restrict__ ei, int* __restrict__ cursor,
                             int* __restrict__ col) {
  int e = blockIdx.x * 256 + threadIdx.x;
  if (e < NM) {
    int src, dst;
    if (e < NE) { src = ei[e]; dst = ei[NE + e]; } else { src = e - NE; dst = e - NE; }
    int pos = atomicAdd(&cursor[dst], 1);
    col[pos] = src;
  }
}

// ---------------- linear transform x -> (xl, xr), wave per node ----------------
__global__ __launch_bounds__(256) void gvae_xform(
    const float* __restrict__ in, int Kin,
    const float* __restrict__ Wl, const float* __restrict__ bl,
    const float* __restrict__ Wr, const float* __restrict__ br,
    float* __restrict__ xl, float* __restrict__ xr) {
  int i = blockIdx.x * 4 + (threadIdx.x >> 6);
  int k = threadIdx.x & 63;
  float la = bl[k], ra = br[k];
  for (int a = 0; a < Kin; a++) {
    float xa = in[i * Kin + a];
    la = fmaf(xa, Wl[a * HD + k], la);
    ra = fmaf(xa, Wr[a * HD + k], ra);
  }
  xl[i * HD + k] = la;
  xr[i * HD + k] = ra;
}

// ---------------- GATv2 aggregate: wave per dst node, online softmax ----------------
__global__ __launch_bounds__(256) void gvae_gat(
    const int* __restrict__ rowptr, const int* __restrict__ col,
    const float* __restrict__ xl, const float* __restrict__ xr,
    const float* __restrict__ att, const float* __restrict__ bias,
    float* __restrict__ hout, float* __restrict__ gh) {
  int i = blockIdx.x * 4 + (threadIdx.x >> 6);
  int lane = threadIdx.x & 63;
  float xrk = xr[i * HD + lane];
  float ak = att[lane];
  int beg = rowptr[i], end = rowptr[i + 1];
  float M = -3.0e38f, D = 0.f, A = 0.f;
  for (int m = beg; m < end; ++m) {
    int s = col[m];
    float xls = xl[s * HD + lane];
    float e = xls + xrk;
    e = fmaxf(e, 0.2f * e);               // leaky_relu(0.2)
    float p = wsum(e * ak);               // logit, all lanes
    float nM = fmaxf(M, p);
    float sc = expf(M - nM);
    float w  = expf(p - nM);
    D = D * sc + w;
    A = fmaf(A, sc, w * xls);
    M = nM;
  }
  float h = fmaxf(A / D + bias[lane], 0.f);  // + bias, relu (both layers relu'd)
  hout[i * HD + lane] = h;
  if (gh) atomicAdd(&gh[lane], h * (1.0f / NN));  // running mean for graph head
}

// ---------------- fused node pipeline: heads + reparam + u/v + decoder MLPs ----------------
__global__ __launch_bounds__(256) void gvae_node(
    const float* __restrict__ h2, const float* __restrict__ eps,
    const float* __restrict__ Wnm, const float* __restrict__ bnm,
    const float* __restrict__ Wnv, const float* __restrict__ bnv,
    const float* __restrict__ We1, const float* __restrict__ be1,
    const float* __restrict__ Wd1, const float* __restrict__ bd1,
    const float* __restrict__ g1, const float* __restrict__ b1,
    const float* __restrict__ Wd2, const float* __restrict__ bd2,
    const float* __restrict__ g2, const float* __restrict__ b2,
    const float* __restrict__ Wd3, const float* __restrict__ bd3,
    const float* __restrict__ Wf1, const float* __restrict__ bf1,
    const float* __restrict__ gf, const float* __restrict__ bfv,
    const float* __restrict__ Wf2, const float* __restrict__ bf2,
    float* __restrict__ uo, float* __restrict__ vo, float* __restrict__ out) {
  int i = blockIdx.x * 4 + (threadIdx.x >> 6);
  int k = threadIdx.x & 63;
  int kk = k & 31;
  float h2k = h2[i * HD + k];

  // node_mu (lanes 0..31) / node_logvar (lanes 32..63)
  const float* W = (k < 32) ? Wnm : Wnv;
  float acc = (k < 32) ? bnm[kk] : bnv[kk];
  for (int a = 0; a < HD; a++) {
    float ha = __shfl(h2k, a, 64);
    acc = fmaf(ha, W[a * LDIM + kk], acc);
  }
  if (k < 32) out[MU_OFF + i * LDIM + kk] = acc;
  else        out[LV_OFF + i * LDIM + kk] = acc;

  // z = mu + eps * exp(0.5*logvar)   (valid in lanes 0..31)
  float lv = __shfl(acc, k + 32, 64);
  float zk = acc + eps[i * LDIM + kk] * expf(0.5f * lv);

  // u = z@We1[:32] + be1 ; v = z@We1[32:]   (edge-pred factorization)
  float ua = be1[k], va = 0.f;
  for (int a = 0; a < LDIM; a++) {
    float za = __shfl(zk, a, 64);
    ua = fmaf(za, We1[a * HD + k], ua);
    va = fmaf(za, We1[(a + LDIM) * HD + k], va);
  }
  uo[i * HD + k] = ua;
  vo[i * HD + k] = va;

  // decoder layer 1: LN(relu(z@Wd1+bd1))
  acc = bd1[k];
  for (int a = 0; a < LDIM; a++) {
    float za = __shfl(zk, a, 64);
    acc = fmaf(za, Wd1[a * HD + k], acc);
  }
  float tv = fmaxf(acc, 0.f);
  float s1 = wsum(tv), s2 = wsum(tv * tv);
  float mu = s1 * (1.0f / 64.0f);
  float var = s2 * (1.0f / 64.0f) - mu * mu;
  float nf1 = (tv - mu) * rsqrtf(var + 1e-5f) * g1[k] + b1[k];

  // decoder layer 2
  acc = bd2[k];
  for (int a = 0; a < HD; a++) {
    float na = __shfl(nf1, a, 64);
    acc = fmaf(na, Wd2[a * HD + k], acc);
  }
  tv = fmaxf(acc, 0.f);
  s1 = wsum(tv); s2 = wsum(tv * tv);
  mu = s1 * (1.0f / 64.0f);
  var = s2 * (1.0f / 64.0f) - mu * mu;
  float nf2 = (tv - mu) * rsqrtf(var + 1e-5f) * g2[k] + b2[k];

  // decoder out: nf3 = nf2@Wd3 + bd3 (27 dims, lanes 0..26)
  acc = 0.f;
  for (int a = 0; a < HD; a++) {
    float na = __shfl(nf2, a, 64);
    if (k < FIN) acc = fmaf(na, Wd3[a * FIN + k], acc);
  }
  float nf3 = (k < FIN) ? (acc + bd3[k]) : 0.f;

  // refinement: LN(relu(cat(nf3, h2)@Wf1 + bf1))
  acc = bf1[k];
  for (int j = 0; j < FIN; j++) {
    float nj = __shfl(nf3, j, 64);
    acc = fmaf(nj, Wf1[j * HD + k], acc);
  }
  for (int a = 0; a < HD; a++) {
    float ha = __shfl(h2k, a, 64);
    acc = fmaf(ha, Wf1[(FIN + a) * HD + k], acc);
  }
  tv = fmaxf(acc, 0.f);
  s1 = wsum(tv); s2 = wsum(tv * tv);
  mu = s1 * (1.0f / 64.0f);
  var = s2 * (1.0f / 64.0f) - mu * mu;
  float rr = (tv - mu) * rsqrtf(var + 1e-5f) * gf[k] + bfv[k];

  // node_features = rr@Wf2 + bf2
  acc = 0.f;
  for (int a = 0; a < HD; a++) {
    float ra = __shfl(rr, a, 64);
    if (k < FIN) acc = fmaf(ra, Wf2[a * FIN + k], acc);
  }
  if (k < FIN) out[i * FIN + k] = acc + bf2[k];
}

// ---------------- graph head (1 wave) ----------------
__global__ void gvae_ghead(const float* __restrict__ gh,
                           const float* __restrict__ Wgm, const float* __restrict__ bgm,
                           const float* __restrict__ Wgv, const float* __restrict__ bgv,
                           float* __restrict__ out) {
  int k = threadIdx.x;
  int kk = k & 31;
  float ghk = gh[k];
  const float* W = (k < 32) ? Wgm : Wgv;
  float acc = (k < 32) ? bgm[kk] : bgv[kk];
  for (int a = 0; a < HD; a++) {
    float ga = __shfl(ghk, a, 64);
    acc = fmaf(ga, W[a * LDIM + kk], acc);
  }
  if (k < 32) out[GMU_OFF + kk] = acc;
  else        out[GLV_OFF + kk] = acc;
}

// ---------------- edge prediction over all i<j pairs ----------------
// logit(i,j) = inv_sigma*(Sc - mu*C1) + C0 with t = relu(u_i + v_j),
// Sc = sum t_k c_k, c_k = lne_g_k*We2_k, C1 = sum c, C0 = sum lne_b*We2 + be2.
__global__ __launch_bounds__(256) void gvae_edge(
    const float* __restrict__ u, const float* __restrict__ v,
    const float* __restrict__ lng, const float* __restrict__ lnb,
    const float* __restrict__ w2, const float* __restrict__ be2,
    float* __restrict__ out) {  // out pre-offset to edge_logits base
  int bj = blockIdx.x, bi = blockIdx.y;
  if (bi > bj) return;
  __shared__ float U[64 * 68];   // stride 68 floats (17 quads, odd) -> conflict-free b128
  __shared__ float V[64 * 64];   // read wave-uniform -> broadcast
  __shared__ float C[64];
  __shared__ float cc[2];
  int t = threadIdx.x;
  const float4* u4p = (const float4*)(u + bi * 64 * HD);
  const float4* v4p = (const float4*)(v + bj * 64 * HD);
  for (int it = 0; it < 4; ++it) {
    int r = t + it * 256;
    int row = r >> 4, q = r & 15;
    float4 uu = u4p[r];
    *(float4*)&U[row * 68 + q * 4] = uu;
    float4 vv = v4p[r];
    *(float4*)&V[row * 64 + q * 4] = vv;
  }
  if (t < 64) {
    float ck = lng[t] * w2[t];
    C[t] = ck;
    float cb = lnb[t] * w2[t];
    float sC = wsum(ck);
    float sB = wsum(cb);
    if (t == 0) { cc[0] = sC; cc[1] = sB + be2[0]; }
  }
  __syncthreads();
  float C1 = cc[0], C0 = cc[1];

  int w = t >> 6, lane = t & 63;          // wave w handles j-group w*16..+16, lane = i_local
  float S1[16], S2[16], Sc[16];
#pragma unroll
  for (int jj = 0; jj < 16; jj++) { S1[jj] = 0.f; S2[jj] = 0.f; Sc[jj] = 0.f; }
  const float* Vb = &V[(w * 16) * 64];
  for (int k4 = 0; k4 < 16; k4++) {
    float4 u4 = *(const float4*)&U[lane * 68 + k4 * 4];
    float4 c4 = *(const float4*)&C[k4 * 4];
#pragma unroll
    for (int jj = 0; jj < 16; jj++) {
      float4 v4 = *(const float4*)&Vb[jj * 64 + k4 * 4];
      float t0 = fmaxf(u4.x + v4.x, 0.f);
      float t1 = fmaxf(u4.y + v4.y, 0.f);
      float t2 = fmaxf(u4.z + v4.z, 0.f);
      float t3 = fmaxf(u4.w + v4.w, 0.f);
      S1[jj] += (t0 + t1) + (t2 + t3);
      S2[jj] = fmaf(t0, t0, fmaf(t1, t1, fmaf(t2, t2, fmaf(t3, t3, S2[jj]))));
      Sc[jj] = fmaf(t0, c4.x, fmaf(t1, c4.y, fmaf(t2, c4.z, fmaf(t3, c4.w, Sc[jj]))));
    }
  }
  int i = bi * 64 + lane;
  int pbase = i * (2 * NN - i - 1) / 2 - i - 1;
  const float inv64 = 1.0f / 64.0f;
#pragma unroll
  for (int jj = 0; jj < 16; jj++) {
    int j = bj * 64 + w * 16 + jj;
    if (j > i) {
      float mu = S1[jj] * inv64;
      float var = fmaf(-mu, mu, S2[jj] * inv64);
      float logit = (Sc[jj] - mu * C1) * rsqrtf(var + 1e-5f) + C0;
      out[pbase + j] = logit;
    }
  }
}

extern "C" void kernel_launch(void* const* d_in, const int* in_sizes, int n_in,
                              void* d_out, int out_size, void* d_ws, size_t ws_size,
                              hipStream_t stream) {
  const float* x    = (const float*)d_in[0];
  const int*   ei   = (const int*)d_in[1];
  const float* eps  = (const float*)d_in[2];
  // d_in[3] = eps_graph: z_graph is computed but unused downstream -> skip
  const float* Wl1  = (const float*)d_in[4];
  const float* bl1  = (const float*)d_in[5];
  const float* Wr1  = (const float*)d_in[6];
  const float* br1  = (const float*)d_in[7];
  const float* att1 = (const float*)d_in[8];
  const float* bias1= (const float*)d_in[9];
  const float* Wl2  = (const float*)d_in[10];
  const float* bl2  = (const float*)d_in[11];
  const float* Wr2  = (const float*)d_in[12];
  const float* br2  = (const float*)d_in[13];
  const float* att2 = (const float*)d_in[14];
  const float* bias2= (const float*)d_in[15];
  const float* Wnm  = (const float*)d_in[16];
  const float* bnm  = (const float*)d_in[17];
  const float* Wnv  = (const float*)d_in[18];
  const float* bnv  = (const float*)d_in[19];
  const float* Wgm  = (const float*)d_in[20];
  const float* bgm  = (const float*)d_in[21];
  const float* Wgv  = (const float*)d_in[22];
  const float* bgv  = (const float*)d_in[23];
  const float* Wd1  = (const float*)d_in[24];
  const float* bd1  = (const float*)d_in[25];
  const float* ln1g = (const float*)d_in[26];
  const float* ln1b = (const float*)d_in[27];
  const float* Wd2  = (const float*)d_in[28];
  const float* bd2  = (const float*)d_in[29];
  const float* ln2g = (const float*)d_in[30];
  const float* ln2b = (const float*)d_in[31];
  const float* Wd3  = (const float*)d_in[32];
  const float* bd3  = (const float*)d_in[33];
  const float* We1  = (const float*)d_in[34];
  const float* be1  = (const float*)d_in[35];
  const float* lneg = (const float*)d_in[36];
  const float* lneb = (const float*)d_in[37];
  const float* We2  = (const float*)d_in[38];
  const float* be2  = (const float*)d_in[39];
  const float* Wf1  = (const float*)d_in[40];
  const float* bf1  = (const float*)d_in[41];
  const float* lnfg = (const float*)d_in[42];
  const float* lnfb = (const float*)d_in[43];
  const float* Wf2  = (const float*)d_in[44];
  const float* bf2  = (const float*)d_in[45];
  float* out = (float*)d_out;

  // workspace layout
  int* deg    = (int*)d_ws;            // N ints (doubles as scatter cursor)
  int* rowptr = deg + NN;              // N+1
  int* col    = rowptr + NN + 1;       // NM
  float* fb  = (float*)(((uintptr_t)(col + NM) + 255) & ~(uintptr_t)255);
  float* xl1 = fb;
  float* xr1 = xl1 + NN * HD;
  float* h1  = xr1 + NN * HD;
  float* xl2 = h1  + NN * HD;
  float* xr2 = xl2 + NN * HD;
  float* h2  = xr2 + NN * HD;
  float* uu  = h2  + NN * HD;
  float* vv  = uu  + NN * HD;
  float* gh  = vv  + NN * HD;          // 64 floats

  hipMemsetAsync(deg, 0, NN * sizeof(int), stream);
  hipMemsetAsync(gh, 0, HD * sizeof(float), stream);

  gvae_degree<<<(NM + 255) / 256, 256, 0, stream>>>(ei, deg);
  gvae_scan<<<1, 256, 0, stream>>>(deg, rowptr);
  gvae_scatter<<<(NM + 255) / 256, 256, 0, stream>>>(ei, deg, col);

  gvae_xform<<<NN / 4, 256, 0, stream>>>(x, FIN, Wl1, bl1, Wr1, br1, xl1, xr1);
  gvae_gat<<<NN / 4, 256, 0, stream>>>(rowptr, col, xl1, xr1, att1, bias1, h1, (float*)nullptr);
  gvae_xform<<<NN / 4, 256, 0, stream>>>(h1, HD, Wl2, bl2, Wr2, br2, xl2, xr2);
  gvae_gat<<<NN / 4, 256, 0, stream>>>(rowptr, col, xl2, xr2, att2, bias2, h2, gh);

  gvae_node<<<NN / 4, 256, 0, stream>>>(h2, eps,
      Wnm, bnm, Wnv, bnv, We1, be1,
      Wd1, bd1, ln1g, ln1b, Wd2, bd2, ln2g, ln2b, Wd3, bd3,
      Wf1, bf1, lnfg, lnfb, Wf2, bf2,
      uu, vv, out);
  gvae_ghead<<<1, 64, 0, stream>>>(gh, Wgm, bgm, Wgv, bgv, out);
  gvae_edge<<<dim3(24, 24), 256, 0, stream>>>(uu, vv, lneg, lneb, We2, be2, out + EL_OFF);
}

// Round 2
// 328.400 us; speedup vs baseline: 1.0503x; 1.0503x over previous
//
#include <hip/hip_runtime.h>

#define NN 1536
#define NE 49152
#define NM (NE + NN)      // edges + self loops = 50688
#define FIN 27
#define HD 64
#define LDIM 32
#define PP 1178880        // NN*(NN-1)/2

#define EL_OFF  (NN*FIN)            // 41472
#define MU_OFF  (EL_OFF + PP)       // 1220352
#define LV_OFF  (MU_OFF + NN*LDIM)  // 1269504
#define GMU_OFF (LV_OFF + NN*LDIM)  // 1318656
#define GLV_OFF (GMU_OFF + LDIM)    // 1318688

__device__ __forceinline__ float wsum(float v) {
#pragma unroll
  for (int m = 1; m < 64; m <<= 1) v += __shfl_xor(v, m, 64);
  return v;
}
__device__ __forceinline__ float wmax(float v) {
#pragma unroll
  for (int m = 1; m < 64; m <<= 1) v = fmaxf(v, __shfl_xor(v, m, 64));
  return v;
}

// ---------------- CSR construction ----------------
__global__ void gvae_degree(const int* __restrict__ ei, int* __restrict__ deg) {
  int e = blockIdx.x * 256 + threadIdx.x;
  if (e < NM) {
    int dst = (e < NE) ? ei[NE + e] : (e - NE);
    atomicAdd(&deg[dst], 1);
  }
}

__global__ void gvae_scan(int* __restrict__ deg, int* __restrict__ rowptr) {
  __shared__ int sh[256];
  int t = threadIdx.x;
  int base = t * 6;
  int v[6]; int s = 0;
#pragma unroll
  for (int r = 0; r < 6; r++) { v[r] = deg[base + r]; s += v[r]; }
  sh[t] = s; __syncthreads();
  for (int off = 1; off < 256; off <<= 1) {
    int x = (t >= off) ? sh[t - off] : 0;
    __syncthreads();
    sh[t] += x;
    __syncthreads();
  }
  int run = sh[t] - s;
#pragma unroll
  for (int r = 0; r < 6; r++) { rowptr[base + r] = run; deg[base + r] = run; run += v[r]; }
  if (t == 255) rowptr[NN] = run;
}

__global__ void gvae_scatter(const int* __restrict__ ei, int* __restrict__ cursor,
                             int* __restrict__ col, int* __restrict__ row) {
  int e = blockIdx.x * 256 + threadIdx.x;
  if (e < NM) {
    int src, dst;
    if (e < NE) { src = ei[e]; dst = ei[NE + e]; } else { src = e - NE; dst = e - NE; }
    int pos = atomicAdd(&cursor[dst], 1);
    col[pos] = src;
    row[pos] = dst;
  }
}

// ---------------- linear transform x -> (xl, xr), wave per node ----------------
__global__ __launch_bounds__(256) void gvae_xform(
    const float* __restrict__ in, int Kin,
    const float* __restrict__ Wl, const float* __restrict__ bl,
    const float* __restrict__ Wr, const float* __restrict__ br,
    float* __restrict__ xl, float* __restrict__ xr) {
  int i = blockIdx.x * 4 + (threadIdx.x >> 6);
  int k = threadIdx.x & 63;
  float la = bl[k], ra = br[k];
  for (int a = 0; a < Kin; a++) {
    float xa = in[i * Kin + a];
    la = fmaf(xa, Wl[a * HD + k], la);
    ra = fmaf(xa, Wr[a * HD + k], ra);
  }
  xl[i * HD + k] = la;
  xr[i * HD + k] = ra;
}

// ---------------- GATv2 phase A: per-edge logits (wave per edge) ----------------
__global__ __launch_bounds__(256) void gvae_logits(
    const int* __restrict__ row, const int* __restrict__ col,
    const float* __restrict__ xl, const float* __restrict__ xr,
    const float* __restrict__ att, float* __restrict__ s) {
  int m = blockIdx.x * 4 + (threadIdx.x >> 6);
  if (m >= NM) return;
  int lane = threadIdx.x & 63;
  int src = col[m], dst = row[m];
  float e = xl[src * HD + lane] + xr[dst * HD + lane];
  e = fmaxf(e, 0.2f * e);                 // leaky_relu(0.2)
  float p = wsum(e * att[lane]);
  if (lane == 0) s[m] = p;
}

// ---------------- GATv2 phase B: softmax + aggregate (wave per node) ----------------
__global__ __launch_bounds__(256) void gvae_aggr(
    const int* __restrict__ rowptr, const int* __restrict__ col,
    const float* __restrict__ s, const float* __restrict__ xl,
    const float* __restrict__ bias, float* __restrict__ hout,
    float* __restrict__ gh) {
  int i = blockIdx.x * 4 + (threadIdx.x >> 6);
  int lane = threadIdx.x & 63;
  int beg = rowptr[i], end = rowptr[i + 1];
  int deg = end - beg;
  float A = 0.f, D = 0.f;
  if (deg <= 64) {
    // logits + col indices live in registers, broadcast via shfl
    float sv = (lane < deg) ? s[beg + lane] : -3.0e38f;
    int   cv = (lane < deg) ? col[beg + lane] : 0;
    float M = wmax(sv);
    float w = (lane < deg) ? expf(sv - M) : 0.f;
    D = wsum(w);
    int m = 0;
    for (; m + 4 <= deg; m += 4) {
      float a0 = __shfl(w, m, 64), a1 = __shfl(w, m + 1, 64);
      float a2 = __shfl(w, m + 2, 64), a3 = __shfl(w, m + 3, 64);
      int c0 = __shfl(cv, m, 64), c1 = __shfl(cv, m + 1, 64);
      int c2 = __shfl(cv, m + 2, 64), c3 = __shfl(cv, m + 3, 64);
      float x0 = xl[c0 * HD + lane], x1 = xl[c1 * HD + lane];
      float x2 = xl[c2 * HD + lane], x3 = xl[c3 * HD + lane];
      A = fmaf(a0, x0, fmaf(a1, x1, fmaf(a2, x2, fmaf(a3, x3, A))));
    }
    for (; m < deg; m++) {
      float a0 = __shfl(w, m, 64);
      int   c0 = __shfl(cv, m, 64);
      A = fmaf(a0, xl[c0 * HD + lane], A);
    }
  } else {
    // general fallback (not hit for this dataset: max deg ~ Poisson(32))
    float lm = -3.0e38f;
    for (int m = beg + lane; m < end; m += 64) lm = fmaxf(lm, s[m]);
    float M = wmax(lm);
    float ld = 0.f;
    for (int m = beg + lane; m < end; m += 64) ld += expf(s[m] - M);
    D = wsum(ld);
    for (int m = beg; m < end; m++) {
      float al = expf(s[m] - M);
      A = fmaf(al, xl[col[m] * HD + lane], A);
    }
  }
  float h = fmaxf(A / D + bias[lane], 0.f);   // + bias, relu
  hout[i * HD + lane] = h;
  if (gh) atomicAdd(&gh[lane], h * (1.0f / NN));
}

// ---------------- fused node pipeline ----------------
__global__ __launch_bounds__(256) void gvae_node(
    const float* __restrict__ h2, const float* __restrict__ eps,
    const float* __restrict__ Wnm, const float* __restrict__ bnm,
    const float* __restrict__ Wnv, const float* __restrict__ bnv,
    const float* __restrict__ We1, const float* __restrict__ be1,
    const float* __restrict__ Wd1, const float* __restrict__ bd1,
    const float* __restrict__ g1, const float* __restrict__ b1,
    const float* __restrict__ Wd2, const float* __restrict__ bd2,
    const float* __restrict__ g2, const float* __restrict__ b2,
    const float* __restrict__ Wd3, const float* __restrict__ bd3,
    const float* __restrict__ Wf1, const float* __restrict__ bf1,
    const float* __restrict__ gf, const float* __restrict__ bfv,
    const float* __restrict__ Wf2, const float* __restrict__ bf2,
    float* __restrict__ uo, float* __restrict__ vo, float* __restrict__ out) {
  int i = blockIdx.x * 4 + (threadIdx.x >> 6);
  int k = threadIdx.x & 63;
  int kk = k & 31;
  float h2k = h2[i * HD + k];

  // node_mu (lanes 0..31) / node_logvar (lanes 32..63)
  const float* W = (k < 32) ? Wnm : Wnv;
  float acc = (k < 32) ? bnm[kk] : bnv[kk];
  for (int a = 0; a < HD; a++) {
    float ha = __shfl(h2k, a, 64);
    acc = fmaf(ha, W[a * LDIM + kk], acc);
  }
  if (k < 32) out[MU_OFF + i * LDIM + kk] = acc;
  else        out[LV_OFF + i * LDIM + kk] = acc;

  // z = mu + eps * exp(0.5*logvar)   (valid in lanes 0..31)
  float lv = __shfl(acc, k + 32, 64);
  float zk = acc + eps[i * LDIM + kk] * expf(0.5f * lv);

  // u = z@We1[:32] + be1 ; v = z@We1[32:]   (edge-pred factorization)
  float ua = be1[k], va = 0.f;
  for (int a = 0; a < LDIM; a++) {
    float za = __shfl(zk, a, 64);
    ua = fmaf(za, We1[a * HD + k], ua);
    va = fmaf(za, We1[(a + LDIM) * HD + k], va);
  }
  uo[i * HD + k] = ua;
  vo[i * HD + k] = va;

  // decoder layer 1: LN(relu(z@Wd1+bd1))
  acc = bd1[k];
  for (int a = 0; a < LDIM; a++) {
    float za = __shfl(zk, a, 64);
    acc = fmaf(za, Wd1[a * HD + k], acc);
  }
  float tv = fmaxf(acc, 0.f);
  float s1 = wsum(tv), s2 = wsum(tv * tv);
  float mu = s1 * (1.0f / 64.0f);
  float var = s2 * (1.0f / 64.0f) - mu * mu;
  float nf1 = (tv - mu) * rsqrtf(var + 1e-5f) * g1[k] + b1[k];

  // decoder layer 2
  acc = bd2[k];
  for (int a = 0; a < HD; a++) {
    float na = __shfl(nf1, a, 64);
    acc = fmaf(na, Wd2[a * HD + k], acc);
  }
  tv = fmaxf(acc, 0.f);
  s1 = wsum(tv); s2 = wsum(tv * tv);
  mu = s1 * (1.0f / 64.0f);
  var = s2 * (1.0f / 64.0f) - mu * mu;
  float nf2 = (tv - mu) * rsqrtf(var + 1e-5f) * g2[k] + b2[k];

  // decoder out: nf3 = nf2@Wd3 + bd3 (27 dims, lanes 0..26)
  acc = 0.f;
  for (int a = 0; a < HD; a++) {
    float na = __shfl(nf2, a, 64);
    if (k < FIN) acc = fmaf(na, Wd3[a * FIN + k], acc);
  }
  float nf3 = (k < FIN) ? (acc + bd3[k]) : 0.f;

  // refinement: LN(relu(cat(nf3, h2)@Wf1 + bf1))
  acc = bf1[k];
  for (int j = 0; j < FIN; j++) {
    float nj = __shfl(nf3, j, 64);
    acc = fmaf(nj, Wf1[j * HD + k], acc);
  }
  for (int a = 0; a < HD; a++) {
    float ha = __shfl(h2k, a, 64);
    acc = fmaf(ha, Wf1[(FIN + a) * HD + k], acc);
  }
  tv = fmaxf(acc, 0.f);
  s1 = wsum(tv); s2 = wsum(tv * tv);
  mu = s1 * (1.0f / 64.0f);
  var = s2 * (1.0f / 64.0f) - mu * mu;
  float rr = (tv - mu) * rsqrtf(var + 1e-5f) * gf[k] + bfv[k];

  // node_features = rr@Wf2 + bf2
  acc = 0.f;
  for (int a = 0; a < HD; a++) {
    float ra = __shfl(rr, a, 64);
    if (k < FIN) acc = fmaf(ra, Wf2[a * FIN + k], acc);
  }
  if (k < FIN) out[i * FIN + k] = acc + bf2[k];
}

// ---------------- graph head (1 wave) ----------------
__global__ void gvae_ghead(const float* __restrict__ gh,
                           const float* __restrict__ Wgm, const float* __restrict__ bgm,
                           const float* __restrict__ Wgv, const float* __restrict__ bgv,
                           float* __restrict__ out) {
  int k = threadIdx.x;
  int kk = k & 31;
  float ghk = gh[k];
  const float* W = (k < 32) ? Wgm : Wgv;
  float acc = (k < 32) ? bgm[kk] : bgv[kk];
  for (int a = 0; a < HD; a++) {
    float ga = __shfl(ghk, a, 64);
    acc = fmaf(ga, W[a * LDIM + kk], acc);
  }
  if (k < 32) out[GMU_OFF + kk] = acc;
  else        out[GLV_OFF + kk] = acc;
}

// ---------------- edge prediction over all i<j pairs ----------------
// logit(i,j) = inv_sigma*(Sc - mu*C1) + C0 with t = relu(u_i + v_j),
// Sc = sum t_k c_k, c_k = lne_g_k*We2_k, C1 = sum c, C0 = sum lne_b*We2 + be2.
// lane = j_local (contiguous stores), 16 i-values per wave in registers.
__global__ __launch_bounds__(256) void gvae_edge(
    const float* __restrict__ u, const float* __restrict__ v,
    const float* __restrict__ lng, const float* __restrict__ lnb,
    const float* __restrict__ w2, const float* __restrict__ be2,
    float* __restrict__ out) {  // out pre-offset to edge_logits base
  int bj = blockIdx.x, bi = blockIdx.y;
  if (bi > bj) return;
  __shared__ float U[64 * 64];   // read wave-uniform -> LDS broadcast
  __shared__ float V[64 * 68];   // lane-varying read, stride 68 (16B/lane sequential)
  __shared__ float C[64];
  __shared__ float cc[2];
  int t = threadIdx.x;
  const float4* u4p = (const float4*)(u + bi * 64 * HD);
  const float4* v4p = (const float4*)(v + bj * 64 * HD);
  for (int it = 0; it < 4; ++it) {
    int r = t + it * 256;
    int row = r >> 4, q = r & 15;
    float4 uu = u4p[r];
    *(float4*)&U[row * 64 + q * 4] = uu;
    float4 vv = v4p[r];
    *(float4*)&V[row * 68 + q * 4] = vv;
  }
  if (t < 64) {
    float ck = lng[t] * w2[t];
    C[t] = ck;
    float cb = lnb[t] * w2[t];
    float sC = wsum(ck);
    float sB = wsum(cb);
    if (t == 0) { cc[0] = sC; cc[1] = sB + be2[0]; }
  }
  __syncthreads();
  float C1 = cc[0], C0 = cc[1];

  int w = t >> 6, lane = t & 63;   // wave w handles i-group w*16..+16; lane = j_local
  float S1[16], S2[16], Sc[16];
#pragma unroll
  for (int ii = 0; ii < 16; ii++) { S1[ii] = 0.f; S2[ii] = 0.f; Sc[ii] = 0.f; }
  const float* Ub = &U[(w * 16) * 64];
  for (int k4 = 0; k4 < 16; k4++) {
    float4 v4 = *(const float4*)&V[lane * 68 + k4 * 4];
    float4 c4 = *(const float4*)&C[k4 * 4];
#pragma unroll
    for (int ii = 0; ii < 16; ii++) {
      float4 u4 = *(const float4*)&Ub[ii * 64 + k4 * 4];
      float t0 = fmaxf(u4.x + v4.x, 0.f);
      float t1 = fmaxf(u4.y + v4.y, 0.f);
      float t2 = fmaxf(u4.z + v4.z, 0.f);
      float t3 = fmaxf(u4.w + v4.w, 0.f);
      S1[ii] += (t0 + t1) + (t2 + t3);
      S2[ii] = fmaf(t0, t0, fmaf(t1, t1, fmaf(t2, t2, fmaf(t3, t3, S2[ii]))));
      Sc[ii] = fmaf(t0, c4.x, fmaf(t1, c4.y, fmaf(t2, c4.z, fmaf(t3, c4.w, Sc[ii]))));
    }
  }
  int j = bj * 64 + lane;
  const float inv64 = 1.0f / 64.0f;
#pragma unroll
  for (int ii = 0; ii < 16; ii++) {
    int i = bi * 64 + w * 16 + ii;
    if (j > i) {
      int pbase = i * (2 * NN - i - 1) / 2 - i - 1;
      float mu = S1[ii] * inv64;
      float var = fmaf(-mu, mu, S2[ii] * inv64);
      float logit = (Sc[ii] - mu * C1) * rsqrtf(var + 1e-5f) + C0;
      out[pbase + j] = logit;   // contiguous across lanes
    }
  }
}

extern "C" void kernel_launch(void* const* d_in, const int* in_sizes, int n_in,
                              void* d_out, int out_size, void* d_ws, size_t ws_size,
                              hipStream_t stream) {
  const float* x    = (const float*)d_in[0];
  const int*   ei   = (const int*)d_in[1];
  const float* eps  = (const float*)d_in[2];
  // d_in[3] = eps_graph: z_graph computed but unused downstream -> skip
  const float* Wl1  = (const float*)d_in[4];
  const float* bl1  = (const float*)d_in[5];
  const float* Wr1  = (const float*)d_in[6];
  const float* br1  = (const float*)d_in[7];
  const float* att1 = (const float*)d_in[8];
  const float* bias1= (const float*)d_in[9];
  const float* Wl2  = (const float*)d_in[10];
  const float* bl2  = (const float*)d_in[11];
  const float* Wr2  = (const float*)d_in[12];
  const float* br2  = (const float*)d_in[13];
  const float* att2 = (const float*)d_in[14];
  const float* bias2= (const float*)d_in[15];
  const float* Wnm  = (const float*)d_in[16];
  const float* bnm  = (const float*)d_in[17];
  const float* Wnv  = (const float*)d_in[18];
  const float* bnv  = (const float*)d_in[19];
  const float* Wgm  = (const float*)d_in[20];
  const float* bgm  = (const float*)d_in[21];
  const float* Wgv  = (const float*)d_in[22];
  const float* bgv  = (const float*)d_in[23];
  const float* Wd1  = (const float*)d_in[24];
  const float* bd1  = (const float*)d_in[25];
  const float* ln1g = (const float*)d_in[26];
  const float* ln1b = (const float*)d_in[27];
  const float* Wd2  = (const float*)d_in[28];
  const float* bd2  = (const float*)d_in[29];
  const float* ln2g = (const float*)d_in[30];
  const float* ln2b = (const float*)d_in[31];
  const float* Wd3  = (const float*)d_in[32];
  const float* bd3  = (const float*)d_in[33];
  const float* We1  = (const float*)d_in[34];
  const float* be1  = (const float*)d_in[35];
  const float* lneg = (const float*)d_in[36];
  const float* lneb = (const float*)d_in[37];
  const float* We2  = (const float*)d_in[38];
  const float* be2  = (const float*)d_in[39];
  const float* Wf1  = (const float*)d_in[40];
  const float* bf1  = (const float*)d_in[41];
  const float* lnfg = (const float*)d_in[42];
  const float* lnfb = (const float*)d_in[43];
  const float* Wf2  = (const float*)d_in[44];
  const float* bf2  = (const float*)d_in[45];
  float* out = (float*)d_out;

  // workspace layout
  int* deg    = (int*)d_ws;            // N ints (doubles as scatter cursor)
  int* rowptr = deg + NN;              // N+1
  int* col    = rowptr + NN + 1;       // NM
  int* row    = col + NM;              // NM
  float* fb  = (float*)(((uintptr_t)(row + NM) + 255) & ~(uintptr_t)255);
  float* xl1 = fb;
  float* xr1 = xl1 + NN * HD;
  float* h1  = xr1 + NN * HD;
  float* xl2 = h1  + NN * HD;
  float* xr2 = xl2 + NN * HD;
  float* h2  = xr2 + NN * HD;
  float* uu  = h2  + NN * HD;
  float* vv  = uu  + NN * HD;
  float* se  = vv  + NN * HD;          // NM edge logits (reused per layer)
  float* gh  = se  + NM;               // 64 floats

  hipMemsetAsync(deg, 0, NN * sizeof(int), stream);
  hipMemsetAsync(gh, 0, HD * sizeof(float), stream);

  gvae_degree<<<(NM + 255) / 256, 256, 0, stream>>>(ei, deg);
  gvae_scan<<<1, 256, 0, stream>>>(deg, rowptr);
  gvae_scatter<<<(NM + 255) / 256, 256, 0, stream>>>(ei, deg, col, row);

  gvae_xform<<<NN / 4, 256, 0, stream>>>(x, FIN, Wl1, bl1, Wr1, br1, xl1, xr1);
  gvae_logits<<<NM / 4, 256, 0, stream>>>(row, col, xl1, xr1, att1, se);
  gvae_aggr<<<NN / 4, 256, 0, stream>>>(rowptr, col, se, xl1, bias1, h1, (float*)nullptr);
  gvae_xform<<<NN / 4, 256, 0, stream>>>(h1, HD, Wl2, bl2, Wr2, br2, xl2, xr2);
  gvae_logits<<<NM / 4, 256, 0, stream>>>(row, col, xl2, xr2, att2, se);
  gvae_aggr<<<NN / 4, 256, 0, stream>>>(rowptr, col, se, xl2, bias2, h2, gh);

  gvae_node<<<NN / 4, 256, 0, stream>>>(h2, eps,
      Wnm, bnm, Wnv, bnv, We1, be1,
      Wd1, bd1, ln1g, ln1b, Wd2, bd2, ln2g, ln2b, Wd3, bd3,
      Wf1, bf1, lnfg, lnfb, Wf2, bf2,
      uu, vv, out);
  gvae_ghead<<<1, 64, 0, stream>>>(gh, Wgm, bgm, Wgv, bgv, out);
  gvae_edge<<<dim3(24, 24), 256, 0, stream>>>(uu, vv, lneg, lneb, We2, be2, out + EL_OFF);
}

// Round 3
// 276.110 us; speedup vs baseline: 1.2492x; 1.1894x over previous
//
#include <hip/hip_runtime.h>

#define NN 1536
#define NE 49152
#define NM (NE + NN)      // edges + self loops = 50688
#define FIN 27
#define HD 64
#define LDIM 32
#define PP 1178880        // NN*(NN-1)/2

#define EL_OFF  (NN*FIN)            // 41472
#define MU_OFF  (EL_OFF + PP)       // 1220352
#define LV_OFF  (MU_OFF + NN*LDIM)  // 1269504
#define GMU_OFF (LV_OFF + NN*LDIM)  // 1318656
#define GLV_OFF (GMU_OFF + LDIM)    // 1318688

__device__ __forceinline__ float wsum(float v) {
#pragma unroll
  for (int m = 1; m < 64; m <<= 1) v += __shfl_xor(v, m, 64);
  return v;
}
__device__ __forceinline__ float wmax(float v) {
#pragma unroll
  for (int m = 1; m < 64; m <<= 1) v = fmaxf(v, __shfl_xor(v, m, 64));
  return v;
}
__device__ __forceinline__ void wsum2(float& a, float& b) {
#pragma unroll
  for (int m = 1; m < 64; m <<= 1) {
    a += __shfl_xor(a, m, 64);
    b += __shfl_xor(b, m, 64);
  }
}
// layernorm over the 64 lanes (x per-lane), returns normalized*g+b
__device__ __forceinline__ float lnorm64(float x, float g, float b) {
  float s1 = x, s2 = x * x;
  wsum2(s1, s2);
  float mu = s1 * (1.0f / 64.0f);
  float var = fmaf(-mu, mu, s2 * (1.0f / 64.0f));
  return (x - mu) * rsqrtf(var + 1e-5f) * g + b;
}

// ---------------- CSR construction ----------------
__global__ void gvae_degree(const int* __restrict__ ei, int* __restrict__ deg) {
  int e = blockIdx.x * 256 + threadIdx.x;
  if (e < NM) {
    int dst = (e < NE) ? ei[NE + e] : (e - NE);
    atomicAdd(&deg[dst], 1);
  }
}

__global__ void gvae_scan(int* __restrict__ deg, int* __restrict__ rowptr) {
  __shared__ int sh[256];
  int t = threadIdx.x;
  int base = t * 6;
  int v[6]; int s = 0;
#pragma unroll
  for (int r = 0; r < 6; r++) { v[r] = deg[base + r]; s += v[r]; }
  sh[t] = s; __syncthreads();
  for (int off = 1; off < 256; off <<= 1) {
    int x = (t >= off) ? sh[t - off] : 0;
    __syncthreads();
    sh[t] += x;
    __syncthreads();
  }
  int run = sh[t] - s;
#pragma unroll
  for (int r = 0; r < 6; r++) { rowptr[base + r] = run; deg[base + r] = run; run += v[r]; }
  if (t == 255) rowptr[NN] = run;
}

__global__ void gvae_scatter(const int* __restrict__ ei, int* __restrict__ cursor,
                             int* __restrict__ col, int* __restrict__ row) {
  int e = blockIdx.x * 256 + threadIdx.x;
  if (e < NM) {
    int src, dst;
    if (e < NE) { src = ei[e]; dst = ei[NE + e]; } else { src = e - NE; dst = e - NE; }
    int pos = atomicAdd(&cursor[dst], 1);
    col[pos] = src;
    row[pos] = dst;
  }
}

// ---------------- linear transform x -> (xl, xr), wave per node ----------------
template <int KIN>
__global__ __launch_bounds__(256) void gvae_xform(
    const float* __restrict__ in,
    const float* __restrict__ Wl, const float* __restrict__ bl,
    const float* __restrict__ Wr, const float* __restrict__ br,
    float* __restrict__ xl, float* __restrict__ xr) {
  int i = blockIdx.x * 4 + (threadIdx.x >> 6);
  int k = threadIdx.x & 63;
  float xv = (k < KIN) ? in[i * KIN + k] : 0.f;
  float l0 = bl[k], l1 = 0.f, r0 = br[k], r1 = 0.f;
#pragma unroll
  for (int a = 0; a < KIN; a += 2) {
    float xa = __shfl(xv, a, 64);
    l0 = fmaf(xa, Wl[a * HD + k], l0);
    r0 = fmaf(xa, Wr[a * HD + k], r0);
    if (a + 1 < KIN) {
      float xb = __shfl(xv, a + 1, 64);
      l1 = fmaf(xb, Wl[(a + 1) * HD + k], l1);
      r1 = fmaf(xb, Wr[(a + 1) * HD + k], r1);
    }
  }
  xl[i * HD + k] = l0 + l1;
  xr[i * HD + k] = r0 + r1;
}

// ---------------- GATv2 phase A: per-edge logits (wave per edge) ----------------
__global__ __launch_bounds__(256) void gvae_logits(
    const int* __restrict__ row, const int* __restrict__ col,
    const float* __restrict__ xl, const float* __restrict__ xr,
    const float* __restrict__ att, float* __restrict__ s) {
  int m = blockIdx.x * 4 + (threadIdx.x >> 6);
  if (m >= NM) return;
  int lane = threadIdx.x & 63;
  int src = col[m], dst = row[m];
  float e = xl[src * HD + lane] + xr[dst * HD + lane];
  e = fmaxf(e, 0.2f * e);                 // leaky_relu(0.2)
  float p = wsum(e * att[lane]);
  if (lane == 0) s[m] = p;
}

// ---------------- GATv2 phase B: softmax + aggregate (wave per node) ----------------
__global__ __launch_bounds__(256) void gvae_aggr(
    const int* __restrict__ rowptr, const int* __restrict__ col,
    const float* __restrict__ s, const float* __restrict__ xl,
    const float* __restrict__ bias, float* __restrict__ hout,
    float* __restrict__ gh) {
  int i = blockIdx.x * 4 + (threadIdx.x >> 6);
  int lane = threadIdx.x & 63;
  int beg = rowptr[i], end = rowptr[i + 1];
  int deg = end - beg;
  float A = 0.f, D = 0.f;
  if (deg <= 64) {
    // logits + col indices live in registers; constant-lane shfl -> readlane
    float sv = (lane < deg) ? s[beg + lane] : -3.0e38f;
    int   cv = (lane < deg) ? col[beg + lane] : 0;
    float M = wmax(sv);
    float w = (lane < deg) ? expf(sv - M) : 0.f;   // w==0 masks dead slots below
    D = wsum(w);
    float A1 = 0.f, A2 = 0.f, A3 = 0.f;
#pragma unroll
    for (int m = 0; m < 64; m += 4) {
      A  = fmaf(__shfl(w, m, 64),     xl[__shfl(cv, m, 64) * HD + lane],     A);
      A1 = fmaf(__shfl(w, m + 1, 64), xl[__shfl(cv, m + 1, 64) * HD + lane], A1);
      A2 = fmaf(__shfl(w, m + 2, 64), xl[__shfl(cv, m + 2, 64) * HD + lane], A2);
      A3 = fmaf(__shfl(w, m + 3, 64), xl[__shfl(cv, m + 3, 64) * HD + lane], A3);
    }
    A = (A + A1) + (A2 + A3);
  } else {
    // general fallback (not hit for this dataset: deg ~ Poisson(33))
    float lm = -3.0e38f;
    for (int m = beg + lane; m < end; m += 64) lm = fmaxf(lm, s[m]);
    float M = wmax(lm);
    float ld = 0.f;
    for (int m = beg + lane; m < end; m += 64) ld += expf(s[m] - M);
    D = wsum(ld);
    for (int m = beg; m < end; m++) {
      float al = expf(s[m] - M);
      A = fmaf(al, xl[col[m] * HD + lane], A);
    }
  }
  float h = fmaxf(A / D + bias[lane], 0.f);   // + bias, relu
  hout[i * HD + lane] = h;
  if (gh) atomicAdd(&gh[lane], h * (1.0f / NN));
}

// ---------------- fused node pipeline ----------------
__global__ __launch_bounds__(256) void gvae_node(
    const float* __restrict__ h2, const float* __restrict__ eps,
    const float* __restrict__ Wnm, const float* __restrict__ bnm,
    const float* __restrict__ Wnv, const float* __restrict__ bnv,
    const float* __restrict__ We1, const float* __restrict__ be1,
    const float* __restrict__ Wd1, const float* __restrict__ bd1,
    const float* __restrict__ g1, const float* __restrict__ b1,
    const float* __restrict__ Wd2, const float* __restrict__ bd2,
    const float* __restrict__ g2, const float* __restrict__ b2,
    const float* __restrict__ Wd3, const float* __restrict__ bd3,
    const float* __restrict__ Wf1, const float* __restrict__ bf1,
    const float* __restrict__ gf, const float* __restrict__ bfv,
    const float* __restrict__ Wf2, const float* __restrict__ bf2,
    float* __restrict__ uo, float* __restrict__ vo, float* __restrict__ out) {
  int i = blockIdx.x * 4 + (threadIdx.x >> 6);
  int k = threadIdx.x & 63;
  int kk = k & 31;
  int kc = (k < FIN) ? k : (FIN - 1);   // clamped index for [*,27] matrices
  float h2k = h2[i * HD + k];

  // node_mu (lanes 0..31) / node_logvar (lanes 32..63)
  const float* W = (k < 32) ? Wnm : Wnv;
  float c0 = (k < 32) ? bnm[kk] : bnv[kk];
  float c1 = 0.f, c2 = 0.f, c3 = 0.f;
#pragma unroll
  for (int a = 0; a < HD; a += 4) {
    c0 = fmaf(__shfl(h2k, a, 64),     W[a * LDIM + kk],       c0);
    c1 = fmaf(__shfl(h2k, a + 1, 64), W[(a + 1) * LDIM + kk], c1);
    c2 = fmaf(__shfl(h2k, a + 2, 64), W[(a + 2) * LDIM + kk], c2);
    c3 = fmaf(__shfl(h2k, a + 3, 64), W[(a + 3) * LDIM + kk], c3);
  }
  float acc = (c0 + c1) + (c2 + c3);
  if (k < 32) out[MU_OFF + i * LDIM + kk] = acc;
  else        out[LV_OFF + i * LDIM + kk] = acc;

  // z = mu + eps * exp(0.5*logvar)   (valid in lanes 0..31)
  float lv = __shfl(acc, k + 32, 64);
  float zk = acc + eps[i * LDIM + kk] * expf(0.5f * lv);

  // u = z@We1[:32] + be1 ; v = z@We1[32:]   (edge-pred factorization)
  float u0 = be1[k], u1 = 0.f, v0 = 0.f, v1 = 0.f;
#pragma unroll
  for (int a = 0; a < LDIM; a += 2) {
    float za = __shfl(zk, a, 64);
    float zb = __shfl(zk, a + 1, 64);
    u0 = fmaf(za, We1[a * HD + k], u0);
    u1 = fmaf(zb, We1[(a + 1) * HD + k], u1);
    v0 = fmaf(za, We1[(a + LDIM) * HD + k], v0);
    v1 = fmaf(zb, We1[(a + 1 + LDIM) * HD + k], v1);
  }
  uo[i * HD + k] = u0 + u1;
  vo[i * HD + k] = v0 + v1;

  // decoder layer 1: LN(relu(z@Wd1+bd1))
  c0 = bd1[k]; c1 = 0.f; c2 = 0.f; c3 = 0.f;
#pragma unroll
  for (int a = 0; a < LDIM; a += 4) {
    c0 = fmaf(__shfl(zk, a, 64),     Wd1[a * HD + k],       c0);
    c1 = fmaf(__shfl(zk, a + 1, 64), Wd1[(a + 1) * HD + k], c1);
    c2 = fmaf(__shfl(zk, a + 2, 64), Wd1[(a + 2) * HD + k], c2);
    c3 = fmaf(__shfl(zk, a + 3, 64), Wd1[(a + 3) * HD + k], c3);
  }
  float nf1 = lnorm64(fmaxf((c0 + c1) + (c2 + c3), 0.f), g1[k], b1[k]);

  // decoder layer 2
  c0 = bd2[k]; c1 = 0.f; c2 = 0.f; c3 = 0.f;
#pragma unroll
  for (int a = 0; a < HD; a += 4) {
    c0 = fmaf(__shfl(nf1, a, 64),     Wd2[a * HD + k],       c0);
    c1 = fmaf(__shfl(nf1, a + 1, 64), Wd2[(a + 1) * HD + k], c1);
    c2 = fmaf(__shfl(nf1, a + 2, 64), Wd2[(a + 2) * HD + k], c2);
    c3 = fmaf(__shfl(nf1, a + 3, 64), Wd2[(a + 3) * HD + k], c3);
  }
  float nf2 = lnorm64(fmaxf((c0 + c1) + (c2 + c3), 0.f), g2[k], b2[k]);

  // decoder out: nf3 = nf2@Wd3 + bd3 (27 dims; lanes >=27 compute garbage via kc)
  c0 = 0.f; c1 = 0.f; c2 = 0.f; c3 = 0.f;
#pragma unroll
  for (int a = 0; a < HD; a += 4) {
    c0 = fmaf(__shfl(nf2, a, 64),     Wd3[a * FIN + kc],       c0);
    c1 = fmaf(__shfl(nf2, a + 1, 64), Wd3[(a + 1) * FIN + kc], c1);
    c2 = fmaf(__shfl(nf2, a + 2, 64), Wd3[(a + 2) * FIN + kc], c2);
    c3 = fmaf(__shfl(nf2, a + 3, 64), Wd3[(a + 3) * FIN + kc], c3);
  }
  float nf3 = (k < FIN) ? ((c0 + c1) + (c2 + c3) + bd3[kc]) : 0.f;

  // refinement: LN(relu(cat(nf3, h2)@Wf1 + bf1))
  c0 = bf1[k]; c1 = 0.f; c2 = 0.f; c3 = 0.f;
#pragma unroll
  for (int j = 0; j < FIN; j++) {
    float nj = __shfl(nf3, j, 64);
    c0 = fmaf(nj, Wf1[j * HD + k], c0);
  }
#pragma unroll
  for (int a = 0; a < HD; a += 4) {
    c0 = fmaf(__shfl(h2k, a, 64),     Wf1[(FIN + a) * HD + k],     c0);
    c1 = fmaf(__shfl(h2k, a + 1, 64), Wf1[(FIN + a + 1) * HD + k], c1);
    c2 = fmaf(__shfl(h2k, a + 2, 64), Wf1[(FIN + a + 2) * HD + k], c2);
    c3 = fmaf(__shfl(h2k, a + 3, 64), Wf1[(FIN + a + 3) * HD + k], c3);
  }
  float rr = lnorm64(fmaxf((c0 + c1) + (c2 + c3), 0.f), gf[k], bfv[k]);

  // node_features = rr@Wf2 + bf2
  c0 = 0.f; c1 = 0.f; c2 = 0.f; c3 = 0.f;
#pragma unroll
  for (int a = 0; a < HD; a += 4) {
    c0 = fmaf(__shfl(rr, a, 64),     Wf2[a * FIN + kc],       c0);
    c1 = fmaf(__shfl(rr, a + 1, 64), Wf2[(a + 1) * FIN + kc], c1);
    c2 = fmaf(__shfl(rr, a + 2, 64), Wf2[(a + 2) * FIN + kc], c2);
    c3 = fmaf(__shfl(rr, a + 3, 64), Wf2[(a + 3) * FIN + kc], c3);
  }
  if (k < FIN) out[i * FIN + k] = (c0 + c1) + (c2 + c3) + bf2[kc];
}

// ---------------- graph head (1 wave) ----------------
__global__ void gvae_ghead(const float* __restrict__ gh,
                           const float* __restrict__ Wgm, const float* __restrict__ bgm,
                           const float* __restrict__ Wgv, const float* __restrict__ bgv,
                           float* __restrict__ out) {
  int k = threadIdx.x;
  int kk = k & 31;
  float ghk = gh[k];
  const float* W = (k < 32) ? Wgm : Wgv;
  float c0 = (k < 32) ? bgm[kk] : bgv[kk];
  float c1 = 0.f, c2 = 0.f, c3 = 0.f;
#pragma unroll
  for (int a = 0; a < HD; a += 4) {
    c0 = fmaf(__shfl(ghk, a, 64),     W[a * LDIM + kk],       c0);
    c1 = fmaf(__shfl(ghk, a + 1, 64), W[(a + 1) * LDIM + kk], c1);
    c2 = fmaf(__shfl(ghk, a + 2, 64), W[(a + 2) * LDIM + kk], c2);
    c3 = fmaf(__shfl(ghk, a + 3, 64), W[(a + 3) * LDIM + kk], c3);
  }
  float acc = (c0 + c1) + (c2 + c3);
  if (k < 32) out[GMU_OFF + kk] = acc;
  else        out[GLV_OFF + kk] = acc;
}

// ---------------- edge prediction over all i<j pairs ----------------
// logit(i,j) = inv_sigma*(Sc - mu*C1) + C0 with t = relu(u_i + v_j),
// Sc = sum t_k c_k, c_k = lne_g_k*We2_k, C1 = sum c, C0 = sum lne_b*We2 + be2.
// lane = j_local (contiguous stores), 16 i-values per wave in registers.
__global__ __launch_bounds__(256) void gvae_edge(
    const float* __restrict__ u, const float* __restrict__ v,
    const float* __restrict__ lng, const float* __restrict__ lnb,
    const float* __restrict__ w2, const float* __restrict__ be2,
    float* __restrict__ out) {  // out pre-offset to edge_logits base
  int bj = blockIdx.x, bi = blockIdx.y;
  if (bi > bj) return;
  __shared__ float U[64 * 64];   // read wave-uniform -> LDS broadcast
  __shared__ float V[64 * 68];   // lane-varying read, stride 68 (16B/lane sequential)
  __shared__ float C[64];
  __shared__ float cc[2];
  int t = threadIdx.x;
  const float4* u4p = (const float4*)(u + bi * 64 * HD);
  const float4* v4p = (const float4*)(v + bj * 64 * HD);
#pragma unroll
  for (int it = 0; it < 4; ++it) {
    int r = t + it * 256;
    int row = r >> 4, q = r & 15;
    float4 uu = u4p[r];
    *(float4*)&U[row * 64 + q * 4] = uu;
    float4 vv = v4p[r];
    *(float4*)&V[row * 68 + q * 4] = vv;
  }
  if (t < 64) {
    float ck = lng[t] * w2[t];
    C[t] = ck;
    float cb = lnb[t] * w2[t];
    float sC = wsum(ck);
    float sB = wsum(cb);
    if (t == 0) { cc[0] = sC; cc[1] = sB + be2[0]; }
  }
  __syncthreads();
  float C1 = cc[0], C0 = cc[1];

  int w = t >> 6, lane = t & 63;   // wave w handles i-group w*16..+16; lane = j_local
  float S1[16], S2[16], Sc[16];
#pragma unroll
  for (int ii = 0; ii < 16; ii++) { S1[ii] = 0.f; S2[ii] = 0.f; Sc[ii] = 0.f; }
  const float* Ub = &U[(w * 16) * 64];
  for (int k4 = 0; k4 < 16; k4++) {
    float4 v4 = *(const float4*)&V[lane * 68 + k4 * 4];
    float4 c4 = *(const float4*)&C[k4 * 4];
#pragma unroll
    for (int ii = 0; ii < 16; ii++) {
      float4 u4 = *(const float4*)&Ub[ii * 64 + k4 * 4];
      float t0 = fmaxf(u4.x + v4.x, 0.f);
      float t1 = fmaxf(u4.y + v4.y, 0.f);
      float t2 = fmaxf(u4.z + v4.z, 0.f);
      float t3 = fmaxf(u4.w + v4.w, 0.f);
      S1[ii] += (t0 + t1) + (t2 + t3);
      S2[ii] = fmaf(t0, t0, fmaf(t1, t1, fmaf(t2, t2, fmaf(t3, t3, S2[ii]))));
      Sc[ii] = fmaf(t0, c4.x, fmaf(t1, c4.y, fmaf(t2, c4.z, fmaf(t3, c4.w, Sc[ii]))));
    }
  }
  int j = bj * 64 + lane;
  const float inv64 = 1.0f / 64.0f;
#pragma unroll
  for (int ii = 0; ii < 16; ii++) {
    int i = bi * 64 + w * 16 + ii;
    if (j > i) {
      int pbase = i * (2 * NN - i - 1) / 2 - i - 1;
      float mu = S1[ii] * inv64;
      float var = fmaf(-mu, mu, S2[ii] * inv64);
      float logit = (Sc[ii] - mu * C1) * rsqrtf(var + 1e-5f) + C0;
      out[pbase + j] = logit;   // contiguous across lanes
    }
  }
}

extern "C" void kernel_launch(void* const* d_in, const int* in_sizes, int n_in,
                              void* d_out, int out_size, void* d_ws, size_t ws_size,
                              hipStream_t stream) {
  const float* x    = (const float*)d_in[0];
  const int*   ei   = (const int*)d_in[1];
  const float* eps  = (const float*)d_in[2];
  // d_in[3] = eps_graph: z_graph computed but unused downstream -> skip
  const float* Wl1  = (const float*)d_in[4];
  const float* bl1  = (const float*)d_in[5];
  const float* Wr1  = (const float*)d_in[6];
  const float* br1  = (const float*)d_in[7];
  const float* att1 = (const float*)d_in[8];
  const float* bias1= (const float*)d_in[9];
  const float* Wl2  = (const float*)d_in[10];
  const float* bl2  = (const float*)d_in[11];
  const float* Wr2  = (const float*)d_in[12];
  const float* br2  = (const float*)d_in[13];
  const float* att2 = (const float*)d_in[14];
  const float* bias2= (const float*)d_in[15];
  const float* Wnm  = (const float*)d_in[16];
  const float* bnm  = (const float*)d_in[17];
  const float* Wnv  = (const float*)d_in[18];
  const float* bnv  = (const float*)d_in[19];
  const float* Wgm  = (const float*)d_in[20];
  const float* bgm  = (const float*)d_in[21];
  const float* Wgv  = (const float*)d_in[22];
  const float* bgv  = (const float*)d_in[23];
  const float* Wd1  = (const float*)d_in[24];
  const float* bd1  = (const float*)d_in[25];
  const float* ln1g = (const float*)d_in[26];
  const float* ln1b = (const float*)d_in[27];
  const float* Wd2  = (const float*)d_in[28];
  const float* bd2  = (const float*)d_in[29];
  const float* ln2g = (const float*)d_in[30];
  const float* ln2b = (const float*)d_in[31];
  const float* Wd3  = (const float*)d_in[32];
  const float* bd3  = (const float*)d_in[33];
  const float* We1  = (const float*)d_in[34];
  const float* be1  = (const float*)d_in[35];
  const float* lneg = (const float*)d_in[36];
  const float* lneb = (const float*)d_in[37];
  const float* We2  = (const float*)d_in[38];
  const float* be2  = (const float*)d_in[39];
  const float* Wf1  = (const float*)d_in[40];
  const float* bf1  = (const float*)d_in[41];
  const float* lnfg = (const float*)d_in[42];
  const float* lnfb = (const float*)d_in[43];
  const float* Wf2  = (const float*)d_in[44];
  const float* bf2  = (const float*)d_in[45];
  float* out = (float*)d_out;

  // workspace layout
  int* deg    = (int*)d_ws;            // N ints (doubles as scatter cursor)
  int* rowptr = deg + NN;              // N+1
  int* col    = rowptr + NN + 1;       // NM
  int* row    = col + NM;              // NM
  float* fb  = (float*)(((uintptr_t)(row + NM) + 255) & ~(uintptr_t)255);
  float* xl1 = fb;
  float* xr1 = xl1 + NN * HD;
  float* h1  = xr1 + NN * HD;
  float* xl2 = h1  + NN * HD;
  float* xr2 = xl2 + NN * HD;
  float* h2  = xr2 + NN * HD;
  float* uu  = h2  + NN * HD;
  float* vv  = uu  + NN * HD;
  float* se  = vv  + NN * HD;          // NM edge logits (reused per layer)
  float* gh  = se  + NM;               // 64 floats

  hipMemsetAsync(deg, 0, NN * sizeof(int), stream);
  hipMemsetAsync(gh, 0, HD * sizeof(float), stream);

  gvae_degree<<<(NM + 255) / 256, 256, 0, stream>>>(ei, deg);
  gvae_scan<<<1, 256, 0, stream>>>(deg, rowptr);
  gvae_scatter<<<(NM + 255) / 256, 256, 0, stream>>>(ei, deg, col, row);

  gvae_xform<FIN><<<NN / 4, 256, 0, stream>>>(x, Wl1, bl1, Wr1, br1, xl1, xr1);
  gvae_logits<<<NM / 4, 256, 0, stream>>>(row, col, xl1, xr1, att1, se);
  gvae_aggr<<<NN / 4, 256, 0, stream>>>(rowptr, col, se, xl1, bias1, h1, (float*)nullptr);
  gvae_xform<HD><<<NN / 4, 256, 0, stream>>>(h1, Wl2, bl2, Wr2, br2, xl2, xr2);
  gvae_logits<<<NM / 4, 256, 0, stream>>>(row, col, xl2, xr2, att2, se);
  gvae_aggr<<<NN / 4, 256, 0, stream>>>(rowptr, col, se, xl2, bias2, h2, gh);

  gvae_node<<<NN / 4, 256, 0, stream>>>(h2, eps,
      Wnm, bnm, Wnv, bnv, We1, be1,
      Wd1, bd1, ln1g, ln1b, Wd2, bd2, ln2g, ln2b, Wd3, bd3,
      Wf1, bf1, lnfg, lnfb, Wf2, bf2,
      uu, vv, out);
  gvae_ghead<<<1, 64, 0, stream>>>(gh, Wgm, bgm, Wgv, bgv, out);
  gvae_edge<<<dim3(24, 24), 256, 0, stream>>>(uu, vv, lneg, lneb, We2, be2, out + EL_OFF);
}